// Round 5
// baseline (611.738 us; speedup 1.0000x reference)
//
#include <hip/hip_runtime.h>
#include <hip/hip_bf16.h>

typedef __bf16 bf16x8_t __attribute__((ext_vector_type(8)));
typedef float f32x4_t __attribute__((ext_vector_type(4)));
using bf16 = __hip_bfloat16;

#define EMB 512
#define NTOK 32768           // B*T = 8*4096
#define NROW 262144          // B*T*H
#define SQRT_M_INV 0.17677669529663687f
#define KNC 16               // kptv token-chunks per (b,h)

// async 16B global -> LDS (wave-uniform base + lane*16; thread-order contiguous)
__device__ __forceinline__ void gload16(const void* g, void* l) {
  __builtin_amdgcn_global_load_lds((const __attribute__((address_space(1))) void*)g,
                                   (__attribute__((address_space(3))) void*)l, 16, 0, 0);
}

// counted wait: let N vmem ops stay in flight; drain LDS queue (race-safe
// across the following raw s_barrier).
template <int N> __device__ __forceinline__ void wait_vm_lgkm0() {
  asm volatile("s_waitcnt vmcnt(%0) lgkmcnt(0)" :: "n"(N) : "memory");
  __builtin_amdgcn_sched_barrier(0);
}

// Branchless GELU: erf via Abramowitz-Stegun 7.1.26 (max abs err 1.5e-7,
// far below bf16 output rounding).
__device__ __forceinline__ float fast_gelu(float v) {
  float u = v * 0.70710678118654752f;
  float a = fabsf(u);
  float tt = __builtin_amdgcn_rcpf(fmaf(0.3275911f, a, 1.0f));
  float p = fmaf(tt, 1.061405429f, -1.453152027f);
  p = fmaf(tt, p, 1.421413741f);
  p = fmaf(tt, p, -0.284496736f);
  p = fmaf(tt, p, 0.254829592f);
  p = p * tt;
  float e = __expf(-a * a);
  float er = fmaf(-p, e, 1.0f);      // erf(|u|)
  er = copysignf(er, u);
  return 0.5f * v * (1.0f + er);
}

// ---------------- fused fp32 -> bf16 for the 4 weight tensors ----------------
__device__ __forceinline__ void cvt4(const float* __restrict__ in,
                                     bf16* __restrict__ out, int i4, int n4) {
  if (i4 < n4) {
    float4 v = ((const float4*)in)[i4];
    alignas(8) bf16 o[4];
    o[0] = __float2bfloat16(v.x); o[1] = __float2bfloat16(v.y);
    o[2] = __float2bfloat16(v.z); o[3] = __float2bfloat16(v.w);
    *(uint2*)(out + i4 * 4) = *(const uint2*)o;
  }
}
__global__ __launch_bounds__(256) void f2b4_kernel(
    const float* __restrict__ a, bf16* __restrict__ oa, int na4,
    const float* __restrict__ b, bf16* __restrict__ ob, int nb4,
    const float* __restrict__ c, bf16* __restrict__ oc, int nc4,
    const float* __restrict__ d, bf16* __restrict__ od, int nd4) {
  int i4 = blockIdx.x * 256 + threadIdx.x;
  cvt4(a, oa, i4, na4);
  cvt4(b, ob, i4, nb4);
  cvt4(c, oc, i4, nc4);
  cvt4(d, od, i4, nd4);
}

// ---------------- LayerNorm (512 cols), fp32 in -> bf16 out ----------------
__global__ __launch_bounds__(256) void ln_kernel(const float* __restrict__ x,
                                                 const float* __restrict__ g,
                                                 const float* __restrict__ bt,
                                                 bf16* __restrict__ out) {
  int lane = threadIdx.x & 63;
  int row = blockIdx.x * 4 + (threadIdx.x >> 6);
  const float* xr = x + (size_t)row * EMB;
  float4 v0 = ((const float4*)xr)[lane * 2];
  float4 v1 = ((const float4*)xr)[lane * 2 + 1];
  float s = v0.x + v0.y + v0.z + v0.w + v1.x + v1.y + v1.z + v1.w;
#pragma unroll
  for (int o = 32; o; o >>= 1) s += __shfl_xor(s, o);
  float mu = s * (1.0f / 512.0f);
  float vs = 0.f, d;
  d = v0.x - mu; vs += d * d;  d = v0.y - mu; vs += d * d;
  d = v0.z - mu; vs += d * d;  d = v0.w - mu; vs += d * d;
  d = v1.x - mu; vs += d * d;  d = v1.y - mu; vs += d * d;
  d = v1.z - mu; vs += d * d;  d = v1.w - mu; vs += d * d;
#pragma unroll
  for (int o = 32; o; o >>= 1) vs += __shfl_xor(vs, o);
  float rstd = rsqrtf(vs * (1.0f / 512.0f) + 1e-5f);
  float4 g0 = ((const float4*)g)[lane * 2], g1 = ((const float4*)g)[lane * 2 + 1];
  float4 b0 = ((const float4*)bt)[lane * 2], b1 = ((const float4*)bt)[lane * 2 + 1];
  alignas(16) bf16 o8[8];
  o8[0] = __float2bfloat16((v0.x - mu) * rstd * g0.x + b0.x);
  o8[1] = __float2bfloat16((v0.y - mu) * rstd * g0.y + b0.y);
  o8[2] = __float2bfloat16((v0.z - mu) * rstd * g0.z + b0.z);
  o8[3] = __float2bfloat16((v0.w - mu) * rstd * g0.w + b0.w);
  o8[4] = __float2bfloat16((v1.x - mu) * rstd * g1.x + b1.x);
  o8[5] = __float2bfloat16((v1.y - mu) * rstd * g1.y + b1.y);
  o8[6] = __float2bfloat16((v1.z - mu) * rstd * g1.z + b1.z);
  o8[7] = __float2bfloat16((v1.w - mu) * rstd * g1.w + b1.w);
  *(uint4*)(out + (size_t)row * EMB + lane * 8) = *(const uint4*)o8;
}

// ---------------- MFMA bf16 GEMM: C = A[M,K] * W[N,K]^T ---------------------
// v5: 4-buffer LDS ring, depth-3 counted vmcnt (exposed latency = L/3),
// unified 64x128 tile -> 48 KB LDS -> 3 blocks/CU for ALL instantiations,
// + T2 XOR slot-swizzle (conflict-free ds_read; swizzled GLOBAL source +
// swizzled read, linear LDS dest as global_load_lds requires).
template <int BM, int BN, int WM, int WN, int OP>
__global__ __launch_bounds__(256) void gemm_bt(const bf16* __restrict__ A,
                                               const bf16* __restrict__ W,
                                               const float* __restrict__ bias,
                                               const float* __restrict__ res,
                                               float* __restrict__ outF,
                                               bf16* __restrict__ outB,
                                               int M, int N, int K) {
  constexpr int BK = 32;
  constexpr int TM = BM / WM, TN = BN / WN;
  constexpr int NI = TM / 16, NJ = TN / 16;
  constexpr int AP = BM * BK / 2048;   // 16B stage loads per thread (A)
  constexpr int WP = BN * BK / 2048;   // 16B stage loads per thread (W)
  constexpr int LPT = AP + WP;         // vmem ops per stage per thread
  alignas(16) __shared__ bf16 As[4][BM * BK];
  alignas(16) __shared__ bf16 Ws[4][BN * BK];
  int t = threadIdx.x;
  int lane = t & 63, wid = t >> 6;
  int wm = wid % WM, wn = wid / WM;
  // XCD-contiguous swizzle (bijective when nwg % 8 == 0).
  int nwg = gridDim.x * gridDim.y;
  int lin = blockIdx.y * gridDim.x + blockIdx.x;
  if ((nwg & 7) == 0) lin = (lin & 7) * (nwg >> 3) + (lin >> 3);
  int bn = (lin % gridDim.x) * BN, bm = (lin / gridDim.x) * BM;
  int lr = lane & 15, lq = lane >> 4;

  // staging geometry: thread t owns (row r0, 16B slot t&3) of each 64-row
  // panel; LDS dest is LINEAR (byte = t*16). The 16B slot is XOR-swizzled
  // against the row on the GLOBAL side; reads use the same involution.
  const int r0 = t >> 2;
  const int c0lin = (t & 3) * 8;                    // linear LDS col (elems)
  const int sc = (r0 >> 1) & 3;                     // per-thread swizzle sel
  const int c0g = ((t & 3) ^ sc) * 8;               // swizzled global col
  const int rsw = (lq ^ ((lr >> 1) & 3)) * 8;       // swizzled read col

  const bf16* ap = A + (size_t)(bm + r0) * K + c0g;
  const bf16* wp = W + (size_t)(bn + r0) * K + c0g;
  const size_t strA = (size_t)64 * K;   // 64-row stride between a thread's loads

  f32x4_t acc[NI][NJ];
#pragma unroll
  for (int i = 0; i < NI; ++i)
#pragma unroll
    for (int j = 0; j < NJ; ++j)
#pragma unroll
      for (int r = 0; r < 4; ++r) acc[i][j][r] = 0.f;

  auto stage = [&](int buf) {
#pragma unroll
    for (int p = 0; p < AP; ++p)
      gload16(ap + (size_t)p * strA, &As[buf][(r0 + p * 64) * BK + c0lin]);
#pragma unroll
    for (int p = 0; p < WP; ++p)
      gload16(wp + (size_t)p * strA, &Ws[buf][(r0 + p * 64) * BK + c0lin]);
    ap += BK;
    wp += BK;
  };
  auto compute = [&](int buf) {
    bf16x8_t afr[NI], bfr[NJ];
#pragma unroll
    for (int i = 0; i < NI; ++i)
      afr[i] = *(const bf16x8_t*)&As[buf][(wm * TM + i * 16 + lr) * BK + rsw];
#pragma unroll
    for (int j = 0; j < NJ; ++j)
      bfr[j] = *(const bf16x8_t*)&Ws[buf][(wn * TN + j * 16 + lr) * BK + rsw];
#pragma unroll
    for (int i = 0; i < NI; ++i)
#pragma unroll
      for (int j = 0; j < NJ; ++j)
        acc[i][j] = __builtin_amdgcn_mfma_f32_16x16x32_bf16(afr[i], bfr[j], acc[i][j], 0, 0, 0);
  };

  const int nt = K / BK;    // >= 16 for all our shapes
  stage(0);
  stage(1);
  stage(2);
  int bc = 0, bs = 3;
  for (int kt = 0; kt < nt - 3; ++kt) {
    // stage(kt) landed (<=2*LPT outstanding leaves only stages kt+1, kt+2 in
    // flight); own ds_reads drained -> safe to cross barrier, overwrite ring
    // slot bs = (kt+3)&3 (last computed at kt-1, all waves past barrier kt).
    wait_vm_lgkm0<2 * LPT>();
    __builtin_amdgcn_s_barrier();
    __builtin_amdgcn_sched_barrier(0);
    stage(bs);                 // tile kt+3 flies under compute of kt..kt+2
    compute(bc);
    bc = (bc + 1) & 3;
    bs = (bs + 1) & 3;
  }
  wait_vm_lgkm0<2 * LPT>();
  __builtin_amdgcn_s_barrier();
  __builtin_amdgcn_sched_barrier(0);
  compute(bc);
  bc = (bc + 1) & 3;
  wait_vm_lgkm0<LPT>();
  __builtin_amdgcn_s_barrier();
  __builtin_amdgcn_sched_barrier(0);
  compute(bc);
  bc = (bc + 1) & 3;
  wait_vm_lgkm0<0>();
  __builtin_amdgcn_s_barrier();
  __builtin_amdgcn_sched_barrier(0);
  compute(bc);

#pragma unroll
  for (int i = 0; i < NI; ++i)
#pragma unroll
    for (int j = 0; j < NJ; ++j) {
      int gn = bn + wn * TN + j * 16 + lr;
      float bv = bias[gn];
#pragma unroll
      for (int r = 0; r < 4; ++r) {
        int gm = bm + wm * TM + i * 16 + lq * 4 + r;
        float v = acc[i][j][r] + bv;
        size_t off = (size_t)gm * N + gn;
        if (OP == 0) {
          outF[off] = v;
        } else if (OP == 1) {
          outF[off] = v + res[off];
        } else {
          outB[off] = __float2bfloat16(fast_gelu(v));
        }
      }
    }
}

// decompose global kqv row (b*4096+t)*8+h -> per-(b,h) contiguous row (b*8+h)*4096+t
__device__ __forceinline__ size_t bh_row(size_t grow) {
  size_t h = grow & 7, bt = grow >> 3;
  size_t b = bt >> 12, tt = bt & 4095;
  return ((b * 8 + h) << 12) + tt;
}

// ---------------- Fused KQV GEMM + prm_exp (all-MFMA) ------------------------
// kp/qp/v written in per-(b,h) contiguous layout: [64 bh][4096 t][{32|64}].
__global__ __launch_bounds__(256) void kqv_prm_kernel(
    const bf16* __restrict__ A,      // [NROW,64] LN1 out
    const bf16* __restrict__ Wk,     // [192,64]
    const float* __restrict__ bias,  // [192]
    const float* __restrict__ wrf,   // [32,64] random features
    float* __restrict__ kp, float* __restrict__ qp,   // [64][4096][32]
    bf16* __restrict__ vout) {                        // [64][4096][64]
  constexpr int LDZ = 136;  // bf16 elems/row: stride 68 dwords -> 2-way max
  constexpr int LDV = 72;
  alignas(16) __shared__ char u_raw[27648];
  bf16* As  = (bf16*)u_raw;               // phase1: 64*32*2  = 4096
  bf16* Ws  = (bf16*)(u_raw + 4096);      // phase1: 192*32*2 = 12288
  bf16* zkq = (bf16*)u_raw;               // phase2: 64*136*2 = 17408
  bf16* vs  = (bf16*)(u_raw + 17408);     // phase2: 64*72*2  = 9216
  float* xd_s = (float*)(u_raw + 26624);  // phase2: 64*2*4   = 512

  int t = threadIdx.x;
  int lane = t & 63, wid = t >> 6;
  int wm = wid & 1, wn = wid >> 1;
  int lr = lane & 15, lq = lane >> 4;
  size_t row0 = (size_t)blockIdx.x * 64;

  bf16x8_t wfrag[2][2];
#pragma unroll
  for (int mt = 0; mt < 2; ++mt)
#pragma unroll
    for (int ks = 0; ks < 2; ++ks) {
      const float* src = wrf + (mt * 16 + lr) * 64 + ks * 32 + lq * 8;
#pragma unroll
      for (int jj = 0; jj < 8; ++jj) wfrag[mt][ks][jj] = (__bf16)src[jj];
    }

  f32x4_t acc[2][6];
#pragma unroll
  for (int i = 0; i < 2; ++i)
#pragma unroll
    for (int j = 0; j < 6; ++j)
#pragma unroll
      for (int r = 0; r < 4; ++r) acc[i][j][r] = 0.f;

  const int r0 = t >> 2, c0 = (t * 8) & 31;
  for (int k0 = 0; k0 < 64; k0 += 32) {
    gload16(&A[(row0 + r0) * 64 + k0 + c0], &As[r0 * 32 + c0]);
#pragma unroll
    for (int p = 0; p < 3; ++p) {
      int r = r0 + p * 64;
      gload16(&Wk[(size_t)r * 64 + k0 + c0], &Ws[r * 32 + c0]);
    }
    __syncthreads();
    bf16x8_t af[2], bfr[6];
#pragma unroll
    for (int i = 0; i < 2; ++i)
      af[i] = *(const bf16x8_t*)&As[(wm * 32 + i * 16 + lr) * 32 + lq * 8];
#pragma unroll
    for (int j = 0; j < 6; ++j)
      bfr[j] = *(const bf16x8_t*)&Ws[(wn * 96 + j * 16 + lr) * 32 + lq * 8];
#pragma unroll
    for (int i = 0; i < 2; ++i)
#pragma unroll
      for (int j = 0; j < 6; ++j)
        acc[i][j] = __builtin_amdgcn_mfma_f32_16x16x32_bf16(af[i], bfr[j], acc[i][j], 0, 0, 0);
    __syncthreads();
  }

#pragma unroll
  for (int i = 0; i < 2; ++i)
#pragma unroll
    for (int j = 0; j < 6; ++j) {
      int col = wn * 96 + j * 16 + lr;
      float bv = bias[col];
      int rowb = wm * 32 + i * 16 + lq * 4;
#pragma unroll
      for (int r = 0; r < 4; ++r) {
        float v = acc[i][j][r] + bv;
        if (col < 128) zkq[(rowb + r) * LDZ + col] = __float2bfloat16(v);
        else           vs[(rowb + r) * LDV + (col - 128)] = __float2bfloat16(v);
      }
    }
  __syncthreads();

  if (t < 128) {
    int r = t & 63, sel = t >> 6;
    const bf16* zr = &zkq[r * LDZ + sel * 64];
    float xd = 0.f;
#pragma unroll
    for (int c = 0; c < 64; c += 8) {
      bf16x8_t z8 = *(const bf16x8_t*)&zr[c];
#pragma unroll
      for (int jj = 0; jj < 8; ++jj) { float f = (float)z8[jj]; xd += f * f; }
    }
    xd_s[r * 2 + sel] = 0.5f * xd;
  }
  __syncthreads();

  // v -> global, per-(b,h) layout
#pragma unroll
  for (int p = 0; p < 2; ++p) {
    int idx = t + p * 256;            // 512 uint4s = 64 rows x 8
    int r = idx >> 3, c8 = idx & 7;
    size_t nr = bh_row(row0 + r);
    *(uint4*)&vout[nr * 64 + c8 * 8] = *(const uint4*)&vs[r * LDV + c8 * 8];
  }

  int sel = wn;
  f32x4_t aw[2][2];
#pragma unroll
  for (int i = 0; i < 2; ++i)
#pragma unroll
    for (int mt = 0; mt < 2; ++mt)
#pragma unroll
      for (int r = 0; r < 4; ++r) aw[i][mt][r] = 0.f;
#pragma unroll
  for (int ks = 0; ks < 2; ++ks) {
    bf16x8_t af2[2];
#pragma unroll
    for (int i = 0; i < 2; ++i)
      af2[i] = *(const bf16x8_t*)&zkq[(wm * 32 + i * 16 + lr) * LDZ + sel * 64 + ks * 32 + lq * 8];
#pragma unroll
    for (int i = 0; i < 2; ++i)
#pragma unroll
      for (int mt = 0; mt < 2; ++mt)
        aw[i][mt] = __builtin_amdgcn_mfma_f32_16x16x32_bf16(af2[i], wfrag[mt][ks], aw[i][mt], 0, 0, 0);
  }
  float* outp = sel ? qp : kp;
#pragma unroll
  for (int i = 0; i < 2; ++i)
#pragma unroll
    for (int r = 0; r < 4; ++r) {
      int row = wm * 32 + i * 16 + lq * 4 + r;
      size_t nr = bh_row(row0 + row);
#pragma unroll
      for (int mt = 0; mt < 2; ++mt) {
        int m = mt * 16 + lr;
        outp[nr * 32 + m] =
            __expf(aw[i][mt][r] - xd_s[row * 2 + sel]) * SQRT_M_INV;
      }
    }
}

// ---------------- kptv + kp_sum partial reduction over T ---------------------
// v2: each thread owns a 4e x 8m tile (vectorized uint2 v-load, 32 FMA/iter),
// 4 token-subsets (one per wave) LDS-reduced; 16 chunks of 256 tokens ->
// 1024 blocks (4/CU). Partial [64e x 32m] + [32 kpsum] per (bh, chunk).
__global__ __launch_bounds__(256) void kptv_kernel(const bf16* __restrict__ v2,
                                                   const float* __restrict__ kp2,
                                                   float* __restrict__ part) {
  int bh = blockIdx.x, chunk = blockIdx.y;   // grid (64, KNC)
  int t = threadIdx.x;
  int ts = t >> 6;          // token subset (wave id)
  int eg = (t >> 2) & 15;   // e-group: 4 e each
  int g  = t & 3;           // m-group: 8 m each
  const int T0 = chunk * 256;
  const bf16* vp = v2 + ((size_t)bh * 4096 + T0) * 64 + eg * 4;
  const float* kpp = kp2 + ((size_t)bh * 4096 + T0) * 32 + g * 8;

  float acc[4][8];
  float accs[8];
#pragma unroll
  for (int e = 0; e < 4; ++e)
#pragma unroll
    for (int m = 0; m < 8; ++m) acc[e][m] = 0.f;
#pragma unroll
  for (int m = 0; m < 8; ++m) accs[m] = 0.f;

#pragma unroll 2
  for (int tok = ts; tok < 256; tok += 4) {
    union { uint2 u; ushort s[4]; } vr;
    vr.u = *(const uint2*)(vp + (size_t)tok * 64);
    float ve[4];
#pragma unroll
    for (int e = 0; e < 4; ++e)
      ve[e] = __uint_as_float((uint32_t)vr.s[e] << 16);
    float4 k0 = *(const float4*)(kpp + (size_t)tok * 32);
    float4 k1 = *(const float4*)(kpp + (size_t)tok * 32 + 4);
    float km[8] = {k0.x, k0.y, k0.z, k0.w, k1.x, k1.y, k1.z, k1.w};
#pragma unroll
    for (int e = 0; e < 4; ++e)
#pragma unroll
      for (int m = 0; m < 8; ++m) acc[e][m] = fmaf(ve[e], km[m], acc[e][m]);
#pragma unroll
    for (int m = 0; m < 8; ++m) accs[m] += km[m];
  }

  // cross-wave (token-subset) reduction through LDS
  __shared__ float red[256][33];    // stride 33: conflict-free scalar rows
  __shared__ float reds[4][4][8];
#pragma unroll
  for (int e = 0; e < 4; ++e)
#pragma unroll
    for (int m = 0; m < 8; ++m) red[t][e * 8 + m] = acc[e][m];
  if (eg == 0) {
#pragma unroll
    for (int m = 0; m < 8; ++m) reds[ts][g][m] = accs[m];
  }
  __syncthreads();

  // 256 threads: slot l = t>>2 (eg,g), q = t&3 picks local e
  int l = t >> 2, q = t & 3;
  int leg = l >> 2, lg = l & 3;
  float o[8];
#pragma unroll
  for (int m = 0; m < 8; ++m)
    o[m] = red[l][q * 8 + m] + red[l + 64][q * 8 + m] +
           red[l + 128][q * 8 + m] + red[l + 192][q * 8 + m];
  float* pp = part + (size_t)(bh * KNC + chunk) * 2080 + (leg * 4 + q) * 32 + lg * 8;
  *(float4*)pp = make_float4(o[0], o[1], o[2], o[3]);
  *(float4*)(pp + 4) = make_float4(o[4], o[5], o[6], o[7]);
  if (t < 32) {
    int g2 = t >> 3, j = t & 7;
    float s = reds[0][g2][j] + reds[1][g2][j] + reds[2][g2][j] + reds[3][g2][j];
    part[(size_t)(bh * KNC + chunk) * 2080 + 2048 + g2 * 8 + j] = s;
  }
}

// ---------------- y = (qp . kptv) / (qp . kpsum), bf16 out -------------------
// v3: (a) cooperative LDS partial-reduction preamble (coalesced, no x4
// redundancy); (b) per-token inv_dd phase (kills the 64x-redundant dd dot);
// (c) double-buffered async qp staging (load grp+1 flies under grp compute);
// (d) deferred stores (retire during next grp's compute, not the barrier).
__global__ __launch_bounds__(256) void y_kernel(const float* __restrict__ qp2,
                                                const float* __restrict__ part,
                                                bf16* __restrict__ y) {
  int bh = blockIdx.x, chunk = blockIdx.y;   // grid (64, 8)
  int b = bh >> 3, h = bh & 7;
  __shared__ float kv_s[64][36];             // stride 36: 16B-aligned rows
  __shared__ float ks_s[32];
  __shared__ float inv_dd[512];
  alignas(16) __shared__ float qp_s[2][16][32];
  int t = threadIdx.x;
  int e = t & 63, iq = t >> 6;
  const int T0 = chunk * 512;
  const size_t qbase = (size_t)bh * 4096 + T0;

  // --- cooperative partial reduction: kv_s[64][32], ks_s[32] ---
  {
    int er = t >> 2, m0 = (t & 3) * 8;
    float4 a0 = make_float4(0.f, 0.f, 0.f, 0.f);
    float4 a1 = make_float4(0.f, 0.f, 0.f, 0.f);
#pragma unroll 4
    for (int c = 0; c < KNC; ++c) {
      const float* pp = part + (size_t)(bh * KNC + c) * 2080 + er * 32 + m0;
      float4 u = *(const float4*)pp;
      float4 v = *(const float4*)(pp + 4);
      a0.x += u.x; a0.y += u.y; a0.z += u.z; a0.w += u.w;
      a1.x += v.x; a1.y += v.y; a1.z += v.z; a1.w += v.w;
    }
    *(float4*)&kv_s[er][m0] = a0;
    *(float4*)&kv_s[er][m0 + 4] = a1;
    if (t < 32) {
      float s = 0.f;
#pragma unroll 4
      for (int c = 0; c < KNC; ++c)
        s += part[(size_t)(bh * KNC + c) * 2080 + 2048 + t];
      ks_s[t] = s;
    }
  }
  __syncthreads();

  float kv[32];
#pragma unroll
  for (int m = 0; m < 32; m += 4) *(float4*)&kv[m] = *(const float4*)&kv_s[e][m];

  // stage grp 0 (async; flies under the inv_dd phase).
  // LDS dest byte-offset = t*16 (contiguous in thread order) as required.
  if (t < 128)
    gload16(qp2 + (qbase + (t >> 3)) * 32 + (t & 7) * 4,
            &qp_s[0][t >> 3][(t & 7) * 4]);

  // --- inv_dd: 2 tokens per thread ---
  {
    float ks[32];
#pragma unroll
    for (int m = 0; m < 32; m += 4) *(float4*)&ks[m] = *(const float4*)&ks_s[m];
#pragma unroll
    for (int p = 0; p < 2; ++p) {
      int tok = t + p * 256;
      const float* qrow = qp2 + (qbase + tok) * 32;
      float dd = 0.f;
#pragma unroll
      for (int m = 0; m < 32; m += 4) {
        float4 qq = *(const float4*)&qrow[m];
        dd += qq.x * ks[m] + qq.y * ks[m + 1] + qq.z * ks[m + 2] + qq.w * ks[m + 3];
      }
      inv_dd[tok] = 1.0f / dd;
    }
  }

  float dreg[4];
  int cur = 0;
  for (int grp = 0; grp < 32; ++grp) {
    __syncthreads();   // drains stage(grp); first iter also covers inv_dd
    if (grp > 0) {     // deferred stores of grp-1: full grp to retire
      int tokp = (grp - 1) * 16 + iq * 4;
#pragma unroll
      for (int i0 = 0; i0 < 4; ++i0)
        y[(size_t)(b * 4096 + T0 + tokp + i0) * EMB + h * 64 + e] =
            __float2bfloat16(dreg[i0]);
    }
    if (grp < 31 && t < 128) {
      int nr = (grp + 1) * 16;
      gload16(qp2 + (qbase + nr + (t >> 3)) * 32 + (t & 7) * 4,
              &qp_s[cur ^ 1][t >> 3][(t & 7) * 4]);
    }
#pragma unroll
    for (int i0 = 0; i0 < 4; ++i0) {
      int i = iq * 4 + i0;
      float dot = 0.f;
#pragma unroll
      for (int m = 0; m < 32; m += 4) {
        float4 qq = *(const float4*)&qp_s[cur][i][m];
        dot += qq.x * kv[m] + qq.y * kv[m + 1] + qq.z * kv[m + 2] + qq.w * kv[m + 3];
      }
      dreg[i0] = dot * inv_dd[grp * 16 + i];
    }
    cur ^= 1;
  }
#pragma unroll
  for (int i0 = 0; i0 < 4; ++i0) {
    int tokp = 31 * 16 + iq * 4 + i0;
    y[(size_t)(b * 4096 + T0 + tokp) * EMB + h * 64 + e] =
        __float2bfloat16(dreg[i0]);
  }
}

extern "C" void kernel_launch(void* const* d_in, const int* in_sizes, int n_in,
                              void* d_out, int out_size, void* d_ws, size_t ws_size,
                              hipStream_t stream) {
  const float* x      = (const float*)d_in[0];
  const float* w      = (const float*)d_in[1];
  const float* kqv_w  = (const float*)d_in[2];
  const float* kqv_b  = (const float*)d_in[3];
  const float* proj_w = (const float*)d_in[4];
  const float* proj_b = (const float*)d_in[5];
  const float* ln1_g  = (const float*)d_in[6];
  const float* ln1_b  = (const float*)d_in[7];
  const float* ln2_g  = (const float*)d_in[8];
  const float* ln2_b  = (const float*)d_in[9];
  const float* mlp_w1 = (const float*)d_in[10];
  const float* mlp_b1 = (const float*)d_in[11];
  const float* mlp_w2 = (const float*)d_in[12];
  const float* mlp_b2 = (const float*)d_in[13];
  float* out = (float*)d_out;

  char* ws = (char*)d_ws;
  size_t off = 0;
  auto alloc = [&](size_t bytes) -> void* {
    void* p = ws + off;
    off = (off + bytes + 255) & ~(size_t)255;
    return p;
  };

  // ~142 MiB total
  bf16* kqv_wb  = (bf16*)alloc(12288 * 2);
  bf16* proj_wb = (bf16*)alloc(262144 * 2);
  bf16* w1b     = (bf16*)alloc(1048576 * 2);
  bf16* w2b     = (bf16*)alloc(1048576 * 2);
  bf16* hb      = (bf16*)alloc((size_t)NTOK * EMB * 2);   // LN1 out; reused as y
  bf16* yb      = hb;
  float* qpb    = (float*)alloc((size_t)NROW * 32 * 4);   // reused as h2 (bf16)
  bf16* h2b     = (bf16*)qpb;
  float* kpb    = (float*)alloc((size_t)NROW * 32 * 4);   // kp; +vb reused as hid
  bf16* hidb    = (bf16*)kpb;                              // spans kpb+vb (67 MB)
  bf16* vb      = (bf16*)alloc((size_t)NROW * 64 * 2);     // contiguous after kpb
  float* partb  = (float*)alloc((size_t)64 * KNC * 2080 * 4);  // kptv partials

  // 1) weights -> bf16 (single fused launch; 4 elems/thread via float4)
  f2b4_kernel<<<1024, 256, 0, stream>>>(kqv_w, kqv_wb, 12288 / 4,
                                        proj_w, proj_wb, 262144 / 4,
                                        mlp_w1, w1b, 1048576 / 4,
                                        mlp_w2, w2b, 1048576 / 4);

  // 2) LN1: x -> h (bf16)
  ln_kernel<<<NTOK / 4, 256, 0, stream>>>(x, ln1_g, ln1_b, hb);

  // 3) fused KQV GEMM + prm_exp -> kp, qp (fp32), v (bf16), per-(b,h) layouts
  kqv_prm_kernel<<<NROW / 64, 256, 0, stream>>>(hb, kqv_wb, kqv_b, w, kpb, qpb, vb);

  // 4) kptv + kp_sum partials (no atomics, no memset)
  kptv_kernel<<<dim3(64, KNC), 256, 0, stream>>>(vb, kpb, partb);

  // 5) y (bf16, token-major [NTOK, 512]) -> reuses hb; sums partials inline
  y_kernel<<<dim3(64, 8), 256, 0, stream>>>(qpb, partb, yb);

  // 6) proj GEMM + residual: d_out = y @ proj_w^T + proj_b + x
  gemm_bt<64, 128, 1, 4, 1><<<dim3(4, NTOK / 64), 256, 0, stream>>>(
      yb, proj_wb, proj_b, x, out, nullptr, NTOK, 512, 512);

  // 7) LN2: d_out -> h2 (bf16, reuses qp region)
  ln_kernel<<<NTOK / 4, 256, 0, stream>>>(out, ln2_g, ln2_b, h2b);

  // 8) MLP in 2 token-chunks of 16384 (hid reuses kp+v regions, 67 MB)
  for (int c = 0; c < 2; ++c) {
    const bf16* h2c = h2b + (size_t)c * 16384 * 512;
    float* outc = out + (size_t)c * 16384 * 512;
    gemm_bt<64, 128, 1, 4, 2><<<dim3(16, 256), 256, 0, stream>>>(
        h2c, w1b, mlp_b1, nullptr, nullptr, hidb, 16384, 2048, 512);
    gemm_bt<64, 128, 1, 4, 1><<<dim3(4, 256), 256, 0, stream>>>(
        hidb, w2b, mlp_b2, outc, outc, nullptr, 16384, 512, 2048);
  }
}

// Round 6
// 548.971 us; speedup vs baseline: 1.1143x; 1.1143x over previous
//
#include <hip/hip_runtime.h>
#include <hip/hip_bf16.h>

typedef __bf16 bf16x8_t __attribute__((ext_vector_type(8)));
typedef float f32x4_t __attribute__((ext_vector_type(4)));
using bf16 = __hip_bfloat16;

#define EMB 512
#define NTOK 32768           // B*T = 8*4096
#define NROW 262144          // B*T*H
#define SQRT_M_INV 0.17677669529663687f
#define KNC 16               // kptv token-chunks per (b,h)

// async 16B global -> LDS (wave-uniform base + lane*16; thread-order contiguous)
__device__ __forceinline__ void gload16(const void* g, void* l) {
  __builtin_amdgcn_global_load_lds((const __attribute__((address_space(1))) void*)g,
                                   (__attribute__((address_space(3))) void*)l, 16, 0, 0);
}

// counted wait: let N vmem ops stay in flight; drain LDS queue (race-safe
// across the following raw s_barrier).
template <int N> __device__ __forceinline__ void wait_vm_lgkm0() {
  asm volatile("s_waitcnt vmcnt(%0) lgkmcnt(0)" :: "n"(N) : "memory");
  __builtin_amdgcn_sched_barrier(0);
}

// Branchless GELU: erf via Abramowitz-Stegun 7.1.26 (max abs err 1.5e-7,
// far below bf16 output rounding).
__device__ __forceinline__ float fast_gelu(float v) {
  float u = v * 0.70710678118654752f;
  float a = fabsf(u);
  float tt = __builtin_amdgcn_rcpf(fmaf(0.3275911f, a, 1.0f));
  float p = fmaf(tt, 1.061405429f, -1.453152027f);
  p = fmaf(tt, p, 1.421413741f);
  p = fmaf(tt, p, -0.284496736f);
  p = fmaf(tt, p, 0.254829592f);
  p = p * tt;
  float e = __expf(-a * a);
  float er = fmaf(-p, e, 1.0f);      // erf(|u|)
  er = copysignf(er, u);
  return 0.5f * v * (1.0f + er);
}

// ---------------- fused fp32 -> bf16 for the 4 weight tensors ----------------
__device__ __forceinline__ void cvt4(const float* __restrict__ in,
                                     bf16* __restrict__ out, int i4, int n4) {
  if (i4 < n4) {
    float4 v = ((const float4*)in)[i4];
    alignas(8) bf16 o[4];
    o[0] = __float2bfloat16(v.x); o[1] = __float2bfloat16(v.y);
    o[2] = __float2bfloat16(v.z); o[3] = __float2bfloat16(v.w);
    *(uint2*)(out + i4 * 4) = *(const uint2*)o;
  }
}
__global__ __launch_bounds__(256) void f2b4_kernel(
    const float* __restrict__ a, bf16* __restrict__ oa, int na4,
    const float* __restrict__ b, bf16* __restrict__ ob, int nb4,
    const float* __restrict__ c, bf16* __restrict__ oc, int nc4,
    const float* __restrict__ d, bf16* __restrict__ od, int nd4) {
  int i4 = blockIdx.x * 256 + threadIdx.x;
  cvt4(a, oa, i4, na4);
  cvt4(b, ob, i4, nb4);
  cvt4(c, oc, i4, nc4);
  cvt4(d, od, i4, nd4);
}

// ---------------- LayerNorm (512 cols), fp32 in -> bf16 out ----------------
__global__ __launch_bounds__(256) void ln_kernel(const float* __restrict__ x,
                                                 const float* __restrict__ g,
                                                 const float* __restrict__ bt,
                                                 bf16* __restrict__ out) {
  int lane = threadIdx.x & 63;
  int row = blockIdx.x * 4 + (threadIdx.x >> 6);
  const float* xr = x + (size_t)row * EMB;
  float4 v0 = ((const float4*)xr)[lane * 2];
  float4 v1 = ((const float4*)xr)[lane * 2 + 1];
  float s = v0.x + v0.y + v0.z + v0.w + v1.x + v1.y + v1.z + v1.w;
#pragma unroll
  for (int o = 32; o; o >>= 1) s += __shfl_xor(s, o);
  float mu = s * (1.0f / 512.0f);
  float vs = 0.f, d;
  d = v0.x - mu; vs += d * d;  d = v0.y - mu; vs += d * d;
  d = v0.z - mu; vs += d * d;  d = v0.w - mu; vs += d * d;
  d = v1.x - mu; vs += d * d;  d = v1.y - mu; vs += d * d;
  d = v1.z - mu; vs += d * d;  d = v1.w - mu; vs += d * d;
#pragma unroll
  for (int o = 32; o; o >>= 1) vs += __shfl_xor(vs, o);
  float rstd = rsqrtf(vs * (1.0f / 512.0f) + 1e-5f);
  float4 g0 = ((const float4*)g)[lane * 2], g1 = ((const float4*)g)[lane * 2 + 1];
  float4 b0 = ((const float4*)bt)[lane * 2], b1 = ((const float4*)bt)[lane * 2 + 1];
  alignas(16) bf16 o8[8];
  o8[0] = __float2bfloat16((v0.x - mu) * rstd * g0.x + b0.x);
  o8[1] = __float2bfloat16((v0.y - mu) * rstd * g0.y + b0.y);
  o8[2] = __float2bfloat16((v0.z - mu) * rstd * g0.z + b0.z);
  o8[3] = __float2bfloat16((v0.w - mu) * rstd * g0.w + b0.w);
  o8[4] = __float2bfloat16((v1.x - mu) * rstd * g1.x + b1.x);
  o8[5] = __float2bfloat16((v1.y - mu) * rstd * g1.y + b1.y);
  o8[6] = __float2bfloat16((v1.z - mu) * rstd * g1.z + b1.z);
  o8[7] = __float2bfloat16((v1.w - mu) * rstd * g1.w + b1.w);
  *(uint4*)(out + (size_t)row * EMB + lane * 8) = *(const uint4*)o8;
}

// ---------------- MFMA bf16 GEMM: C = A[M,K] * W[N,K]^T ---------------------
// v6 = r4 config (proven best): 3-buffer LDS ring, depth-2 counted vmcnt,
// T2 XOR slot-swizzle (0 bank conflicts), XCD-contiguous block swizzle,
// + T5 s_setprio around the MFMA cluster (cross-block role diversity:
// co-resident blocks are at different ring phases).
template <int BM, int BN, int WM, int WN, int OP>
__global__ __launch_bounds__(256) void gemm_bt(const bf16* __restrict__ A,
                                               const bf16* __restrict__ W,
                                               const float* __restrict__ bias,
                                               const float* __restrict__ res,
                                               float* __restrict__ outF,
                                               bf16* __restrict__ outB,
                                               int M, int N, int K) {
  constexpr int BK = 32;
  constexpr int TM = BM / WM, TN = BN / WN;
  constexpr int NI = TM / 16, NJ = TN / 16;
  constexpr int AP = BM * BK / 2048;   // 16B stage loads per thread (A)
  constexpr int WP = BN * BK / 2048;   // 16B stage loads per thread (W)
  constexpr int LPT = AP + WP;         // vmem ops per stage per thread
  alignas(16) __shared__ bf16 As[3][BM * BK];
  alignas(16) __shared__ bf16 Ws[3][BN * BK];
  int t = threadIdx.x;
  int lane = t & 63, wid = t >> 6;
  int wm = wid % WM, wn = wid / WM;
  // XCD-contiguous swizzle (bijective when nwg % 8 == 0).
  int nwg = gridDim.x * gridDim.y;
  int lin = blockIdx.y * gridDim.x + blockIdx.x;
  if ((nwg & 7) == 0) lin = (lin & 7) * (nwg >> 3) + (lin >> 3);
  int bn = (lin % gridDim.x) * BN, bm = (lin / gridDim.x) * BM;
  int lr = lane & 15, lq = lane >> 4;

  // staging geometry: thread t owns (row r0, 16B slot t&3) of each 64-row
  // panel; LDS dest is LINEAR (byte = t*16). The 16B slot is XOR-swizzled
  // against the row on the GLOBAL side; reads use the same involution.
  const int r0 = t >> 2;
  const int c0lin = (t & 3) * 8;                    // linear LDS col (elems)
  const int sc = (r0 >> 1) & 3;                     // per-thread swizzle sel
  const int c0g = ((t & 3) ^ sc) * 8;               // swizzled global col
  const int rsw = (lq ^ ((lr >> 1) & 3)) * 8;       // swizzled read col

  const bf16* ap = A + (size_t)(bm + r0) * K + c0g;
  const bf16* wp = W + (size_t)(bn + r0) * K + c0g;
  const size_t strA = (size_t)64 * K;   // 64-row stride between a thread's loads

  f32x4_t acc[NI][NJ];
#pragma unroll
  for (int i = 0; i < NI; ++i)
#pragma unroll
    for (int j = 0; j < NJ; ++j)
#pragma unroll
      for (int r = 0; r < 4; ++r) acc[i][j][r] = 0.f;

  auto stage = [&](int buf) {
#pragma unroll
    for (int p = 0; p < AP; ++p)
      gload16(ap + (size_t)p * strA, &As[buf][(r0 + p * 64) * BK + c0lin]);
#pragma unroll
    for (int p = 0; p < WP; ++p)
      gload16(wp + (size_t)p * strA, &Ws[buf][(r0 + p * 64) * BK + c0lin]);
    ap += BK;
    wp += BK;
  };
  auto compute = [&](int buf) {
    bf16x8_t afr[NI], bfr[NJ];
#pragma unroll
    for (int i = 0; i < NI; ++i)
      afr[i] = *(const bf16x8_t*)&As[buf][(wm * TM + i * 16 + lr) * BK + rsw];
#pragma unroll
    for (int j = 0; j < NJ; ++j)
      bfr[j] = *(const bf16x8_t*)&Ws[buf][(wn * TN + j * 16 + lr) * BK + rsw];
    __builtin_amdgcn_s_setprio(1);
#pragma unroll
    for (int i = 0; i < NI; ++i)
#pragma unroll
      for (int j = 0; j < NJ; ++j)
        acc[i][j] = __builtin_amdgcn_mfma_f32_16x16x32_bf16(afr[i], bfr[j], acc[i][j], 0, 0, 0);
    __builtin_amdgcn_s_setprio(0);
  };

  const int nt = K / BK;    // >= 16 for all our shapes
  stage(0);
  stage(1);
  int bc = 0, bs = 2;
  for (int kt = 0; kt < nt - 2; ++kt) {
    // stage(kt) landed (<=LPT outstanding leaves only stage(kt+1) in flight);
    // own ds_reads drained -> safe to cross barrier and overwrite ring slot.
    wait_vm_lgkm0<LPT>();
    __builtin_amdgcn_s_barrier();
    __builtin_amdgcn_sched_barrier(0);
    stage(bs);                 // tile kt+2 flies under compute of kt, kt+1
    compute(bc);
    bc = (bc == 2) ? 0 : bc + 1;
    bs = (bs == 2) ? 0 : bs + 1;
  }
  wait_vm_lgkm0<LPT>();
  __builtin_amdgcn_s_barrier();
  __builtin_amdgcn_sched_barrier(0);
  compute(bc);
  bc = (bc == 2) ? 0 : bc + 1;
  wait_vm_lgkm0<0>();
  __builtin_amdgcn_s_barrier();
  __builtin_amdgcn_sched_barrier(0);
  compute(bc);

#pragma unroll
  for (int i = 0; i < NI; ++i)
#pragma unroll
    for (int j = 0; j < NJ; ++j) {
      int gn = bn + wn * TN + j * 16 + lr;
      float bv = bias[gn];
#pragma unroll
      for (int r = 0; r < 4; ++r) {
        int gm = bm + wm * TM + i * 16 + lq * 4 + r;
        float v = acc[i][j][r] + bv;
        size_t off = (size_t)gm * N + gn;
        if (OP == 0) {
          outF[off] = v;
        } else if (OP == 1) {
          outF[off] = v + res[off];
        } else {
          outB[off] = __float2bfloat16(fast_gelu(v));
        }
      }
    }
}

// decompose global kqv row (b*4096+t)*8+h -> per-(b,h) contiguous row (b*8+h)*4096+t
__device__ __forceinline__ size_t bh_row(size_t grow) {
  size_t h = grow & 7, bt = grow >> 3;
  size_t b = bt >> 12, tt = bt & 4095;
  return ((b * 8 + h) << 12) + tt;
}

// ---------------- Fused KQV GEMM + prm_exp (all-MFMA) ------------------------
// kp/qp/v written in per-(b,h) contiguous layout: [64 bh][4096 t][{32|64}].
__global__ __launch_bounds__(256) void kqv_prm_kernel(
    const bf16* __restrict__ A,      // [NROW,64] LN1 out
    const bf16* __restrict__ Wk,     // [192,64]
    const float* __restrict__ bias,  // [192]
    const float* __restrict__ wrf,   // [32,64] random features
    float* __restrict__ kp, float* __restrict__ qp,   // [64][4096][32]
    bf16* __restrict__ vout) {                        // [64][4096][64]
  constexpr int LDZ = 136;  // bf16 elems/row: stride 68 dwords -> 2-way max
  constexpr int LDV = 72;
  alignas(16) __shared__ char u_raw[27648];
  bf16* As  = (bf16*)u_raw;               // phase1: 64*32*2  = 4096
  bf16* Ws  = (bf16*)(u_raw + 4096);      // phase1: 192*32*2 = 12288
  bf16* zkq = (bf16*)u_raw;               // phase2: 64*136*2 = 17408
  bf16* vs  = (bf16*)(u_raw + 17408);     // phase2: 64*72*2  = 9216
  float* xd_s = (float*)(u_raw + 26624);  // phase2: 64*2*4   = 512

  int t = threadIdx.x;
  int lane = t & 63, wid = t >> 6;
  int wm = wid & 1, wn = wid >> 1;
  int lr = lane & 15, lq = lane >> 4;
  size_t row0 = (size_t)blockIdx.x * 64;

  bf16x8_t wfrag[2][2];
#pragma unroll
  for (int mt = 0; mt < 2; ++mt)
#pragma unroll
    for (int ks = 0; ks < 2; ++ks) {
      const float* src = wrf + (mt * 16 + lr) * 64 + ks * 32 + lq * 8;
#pragma unroll
      for (int jj = 0; jj < 8; ++jj) wfrag[mt][ks][jj] = (__bf16)src[jj];
    }

  f32x4_t acc[2][6];
#pragma unroll
  for (int i = 0; i < 2; ++i)
#pragma unroll
    for (int j = 0; j < 6; ++j)
#pragma unroll
      for (int r = 0; r < 4; ++r) acc[i][j][r] = 0.f;

  const int r0 = t >> 2, c0 = (t * 8) & 31;
  for (int k0 = 0; k0 < 64; k0 += 32) {
    gload16(&A[(row0 + r0) * 64 + k0 + c0], &As[r0 * 32 + c0]);
#pragma unroll
    for (int p = 0; p < 3; ++p) {
      int r = r0 + p * 64;
      gload16(&Wk[(size_t)r * 64 + k0 + c0], &Ws[r * 32 + c0]);
    }
    __syncthreads();
    bf16x8_t af[2], bfr[6];
#pragma unroll
    for (int i = 0; i < 2; ++i)
      af[i] = *(const bf16x8_t*)&As[(wm * 32 + i * 16 + lr) * 32 + lq * 8];
#pragma unroll
    for (int j = 0; j < 6; ++j)
      bfr[j] = *(const bf16x8_t*)&Ws[(wn * 96 + j * 16 + lr) * 32 + lq * 8];
#pragma unroll
    for (int i = 0; i < 2; ++i)
#pragma unroll
      for (int j = 0; j < 6; ++j)
        acc[i][j] = __builtin_amdgcn_mfma_f32_16x16x32_bf16(af[i], bfr[j], acc[i][j], 0, 0, 0);
    __syncthreads();
  }

#pragma unroll
  for (int i = 0; i < 2; ++i)
#pragma unroll
    for (int j = 0; j < 6; ++j) {
      int col = wn * 96 + j * 16 + lr;
      float bv = bias[col];
      int rowb = wm * 32 + i * 16 + lq * 4;
#pragma unroll
      for (int r = 0; r < 4; ++r) {
        float v = acc[i][j][r] + bv;
        if (col < 128) zkq[(rowb + r) * LDZ + col] = __float2bfloat16(v);
        else           vs[(rowb + r) * LDV + (col - 128)] = __float2bfloat16(v);
      }
    }
  __syncthreads();

  if (t < 128) {
    int r = t & 63, sel = t >> 6;
    const bf16* zr = &zkq[r * LDZ + sel * 64];
    float xd = 0.f;
#pragma unroll
    for (int c = 0; c < 64; c += 8) {
      bf16x8_t z8 = *(const bf16x8_t*)&zr[c];
#pragma unroll
      for (int jj = 0; jj < 8; ++jj) { float f = (float)z8[jj]; xd += f * f; }
    }
    xd_s[r * 2 + sel] = 0.5f * xd;
  }
  __syncthreads();

  // v -> global, per-(b,h) layout
#pragma unroll
  for (int p = 0; p < 2; ++p) {
    int idx = t + p * 256;            // 512 uint4s = 64 rows x 8
    int r = idx >> 3, c8 = idx & 7;
    size_t nr = bh_row(row0 + r);
    *(uint4*)&vout[nr * 64 + c8 * 8] = *(const uint4*)&vs[r * LDV + c8 * 8];
  }

  int sel = wn;
  f32x4_t aw[2][2];
#pragma unroll
  for (int i = 0; i < 2; ++i)
#pragma unroll
    for (int mt = 0; mt < 2; ++mt)
#pragma unroll
      for (int r = 0; r < 4; ++r) aw[i][mt][r] = 0.f;
#pragma unroll
  for (int ks = 0; ks < 2; ++ks) {
    bf16x8_t af2[2];
#pragma unroll
    for (int i = 0; i < 2; ++i)
      af2[i] = *(const bf16x8_t*)&zkq[(wm * 32 + i * 16 + lr) * LDZ + sel * 64 + ks * 32 + lq * 8];
#pragma unroll
    for (int i = 0; i < 2; ++i)
#pragma unroll
      for (int mt = 0; mt < 2; ++mt)
        aw[i][mt] = __builtin_amdgcn_mfma_f32_16x16x32_bf16(af2[i], wfrag[mt][ks], aw[i][mt], 0, 0, 0);
  }
  float* outp = sel ? qp : kp;
#pragma unroll
  for (int i = 0; i < 2; ++i)
#pragma unroll
    for (int r = 0; r < 4; ++r) {
      int row = wm * 32 + i * 16 + lq * 4 + r;
      size_t nr = bh_row(row0 + row);
#pragma unroll
      for (int mt = 0; mt < 2; ++mt) {
        int m = mt * 16 + lr;
        outp[nr * 32 + m] =
            __expf(aw[i][mt][r] - xd_s[row * 2 + sel]) * SQRT_M_INV;
      }
    }
}

// ---------------- kptv + kp_sum partial reduction over T ---------------------
// v2: each thread owns a 4e x 8m tile (vectorized uint2 v-load, 32 FMA/iter),
// 4 token-subsets (one per wave) LDS-reduced; 16 chunks of 256 tokens ->
// 1024 blocks (4/CU). Partial [64e x 32m] + [32 kpsum] per (bh, chunk).
__global__ __launch_bounds__(256) void kptv_kernel(const bf16* __restrict__ v2,
                                                   const float* __restrict__ kp2,
                                                   float* __restrict__ part) {
  int bh = blockIdx.x, chunk = blockIdx.y;   // grid (64, KNC)
  int t = threadIdx.x;
  int ts = t >> 6;          // token subset (wave id)
  int eg = (t >> 2) & 15;   // e-group: 4 e each
  int g  = t & 3;           // m-group: 8 m each
  const int T0 = chunk * 256;
  const bf16* vp = v2 + ((size_t)bh * 4096 + T0) * 64 + eg * 4;
  const float* kpp = kp2 + ((size_t)bh * 4096 + T0) * 32 + g * 8;

  float acc[4][8];
  float accs[8];
#pragma unroll
  for (int e = 0; e < 4; ++e)
#pragma unroll
    for (int m = 0; m < 8; ++m) acc[e][m] = 0.f;
#pragma unroll
  for (int m = 0; m < 8; ++m) accs[m] = 0.f;

#pragma unroll 2
  for (int tok = ts; tok < 256; tok += 4) {
    union { uint2 u; ushort s[4]; } vr;
    vr.u = *(const uint2*)(vp + (size_t)tok * 64);
    float ve[4];
#pragma unroll
    for (int e = 0; e < 4; ++e)
      ve[e] = __uint_as_float((uint32_t)vr.s[e] << 16);
    float4 k0 = *(const float4*)(kpp + (size_t)tok * 32);
    float4 k1 = *(const float4*)(kpp + (size_t)tok * 32 + 4);
    float km[8] = {k0.x, k0.y, k0.z, k0.w, k1.x, k1.y, k1.z, k1.w};
#pragma unroll
    for (int e = 0; e < 4; ++e)
#pragma unroll
      for (int m = 0; m < 8; ++m) acc[e][m] = fmaf(ve[e], km[m], acc[e][m]);
#pragma unroll
    for (int m = 0; m < 8; ++m) accs[m] += km[m];
  }

  // cross-wave (token-subset) reduction through LDS
  __shared__ float red[256][33];    // stride 33: conflict-free scalar rows
  __shared__ float reds[4][4][8];
#pragma unroll
  for (int e = 0; e < 4; ++e)
#pragma unroll
    for (int m = 0; m < 8; ++m) red[t][e * 8 + m] = acc[e][m];
  if (eg == 0) {
#pragma unroll
    for (int m = 0; m < 8; ++m) reds[ts][g][m] = accs[m];
  }
  __syncthreads();

  // 256 threads: slot l = t>>2 (eg,g), q = t&3 picks local e
  int l = t >> 2, q = t & 3;
  int leg = l >> 2, lg = l & 3;
  float o[8];
#pragma unroll
  for (int m = 0; m < 8; ++m)
    o[m] = red[l][q * 8 + m] + red[l + 64][q * 8 + m] +
           red[l + 128][q * 8 + m] + red[l + 192][q * 8 + m];
  float* pp = part + (size_t)(bh * KNC + chunk) * 2080 + (leg * 4 + q) * 32 + lg * 8;
  *(float4*)pp = make_float4(o[0], o[1], o[2], o[3]);
  *(float4*)(pp + 4) = make_float4(o[4], o[5], o[6], o[7]);
  if (t < 32) {
    int g2 = t >> 3, j = t & 7;
    float s = reds[0][g2][j] + reds[1][g2][j] + reds[2][g2][j] + reds[3][g2][j];
    part[(size_t)(bh * KNC + chunk) * 2080 + 2048 + g2 * 8 + j] = s;
  }
}

// ---------------- y = (qp . kptv) / (qp . kpsum), bf16 out -------------------
// v3: (a) cooperative LDS partial-reduction preamble (coalesced, no x4
// redundancy); (b) per-token inv_dd phase (kills the 64x-redundant dd dot);
// (c) double-buffered async qp staging (load grp+1 flies under grp compute);
// (d) deferred stores (retire during next grp's compute, not the barrier).
__global__ __launch_bounds__(256) void y_kernel(const float* __restrict__ qp2,
                                                const float* __restrict__ part,
                                                bf16* __restrict__ y) {
  int bh = blockIdx.x, chunk = blockIdx.y;   // grid (64, 8)
  int b = bh >> 3, h = bh & 7;
  __shared__ float kv_s[64][36];             // stride 36: 16B-aligned rows
  __shared__ float ks_s[32];
  __shared__ float inv_dd[512];
  alignas(16) __shared__ float qp_s[2][16][32];
  int t = threadIdx.x;
  int e = t & 63, iq = t >> 6;
  const int T0 = chunk * 512;
  const size_t qbase = (size_t)bh * 4096 + T0;

  // --- cooperative partial reduction: kv_s[64][32], ks_s[32] ---
  {
    int er = t >> 2, m0 = (t & 3) * 8;
    float4 a0 = make_float4(0.f, 0.f, 0.f, 0.f);
    float4 a1 = make_float4(0.f, 0.f, 0.f, 0.f);
#pragma unroll 4
    for (int c = 0; c < KNC; ++c) {
      const float* pp = part + (size_t)(bh * KNC + c) * 2080 + er * 32 + m0;
      float4 u = *(const float4*)pp;
      float4 v = *(const float4*)(pp + 4);
      a0.x += u.x; a0.y += u.y; a0.z += u.z; a0.w += u.w;
      a1.x += v.x; a1.y += v.y; a1.z += v.z; a1.w += v.w;
    }
    *(float4*)&kv_s[er][m0] = a0;
    *(float4*)&kv_s[er][m0 + 4] = a1;
    if (t < 32) {
      float s = 0.f;
#pragma unroll 4
      for (int c = 0; c < KNC; ++c)
        s += part[(size_t)(bh * KNC + c) * 2080 + 2048 + t];
      ks_s[t] = s;
    }
  }
  __syncthreads();

  float kv[32];
#pragma unroll
  for (int m = 0; m < 32; m += 4) *(float4*)&kv[m] = *(const float4*)&kv_s[e][m];

  // stage grp 0 (async; flies under the inv_dd phase).
  // LDS dest byte-offset = t*16 (contiguous in thread order) as required.
  if (t < 128)
    gload16(qp2 + (qbase + (t >> 3)) * 32 + (t & 7) * 4,
            &qp_s[0][t >> 3][(t & 7) * 4]);

  // --- inv_dd: 2 tokens per thread ---
  {
    float ks[32];
#pragma unroll
    for (int m = 0; m < 32; m += 4) *(float4*)&ks[m] = *(const float4*)&ks_s[m];
#pragma unroll
    for (int p = 0; p < 2; ++p) {
      int tok = t + p * 256;
      const float* qrow = qp2 + (qbase + tok) * 32;
      float dd = 0.f;
#pragma unroll
      for (int m = 0; m < 32; m += 4) {
        float4 qq = *(const float4*)&qrow[m];
        dd += qq.x * ks[m] + qq.y * ks[m + 1] + qq.z * ks[m + 2] + qq.w * ks[m + 3];
      }
      inv_dd[tok] = 1.0f / dd;
    }
  }

  float dreg[4];
  int cur = 0;
  for (int grp = 0; grp < 32; ++grp) {
    __syncthreads();   // drains stage(grp); first iter also covers inv_dd
    if (grp > 0) {     // deferred stores of grp-1: full grp to retire
      int tokp = (grp - 1) * 16 + iq * 4;
#pragma unroll
      for (int i0 = 0; i0 < 4; ++i0)
        y[(size_t)(b * 4096 + T0 + tokp + i0) * EMB + h * 64 + e] =
            __float2bfloat16(dreg[i0]);
    }
    if (grp < 31 && t < 128) {
      int nr = (grp + 1) * 16;
      gload16(qp2 + (qbase + nr + (t >> 3)) * 32 + (t & 7) * 4,
              &qp_s[cur ^ 1][t >> 3][(t & 7) * 4]);
    }
#pragma unroll
    for (int i0 = 0; i0 < 4; ++i0) {
      int i = iq * 4 + i0;
      float dot = 0.f;
#pragma unroll
      for (int m = 0; m < 32; m += 4) {
        float4 qq = *(const float4*)&qp_s[cur][i][m];
        dot += qq.x * kv[m] + qq.y * kv[m + 1] + qq.z * kv[m + 2] + qq.w * kv[m + 3];
      }
      dreg[i0] = dot * inv_dd[grp * 16 + i];
    }
    cur ^= 1;
  }
#pragma unroll
  for (int i0 = 0; i0 < 4; ++i0) {
    int tokp = 31 * 16 + iq * 4 + i0;
    y[(size_t)(b * 4096 + T0 + tokp) * EMB + h * 64 + e] =
        __float2bfloat16(dreg[i0]);
  }
}

extern "C" void kernel_launch(void* const* d_in, const int* in_sizes, int n_in,
                              void* d_out, int out_size, void* d_ws, size_t ws_size,
                              hipStream_t stream) {
  const float* x      = (const float*)d_in[0];
  const float* w      = (const float*)d_in[1];
  const float* kqv_w  = (const float*)d_in[2];
  const float* kqv_b  = (const float*)d_in[3];
  const float* proj_w = (const float*)d_in[4];
  const float* proj_b = (const float*)d_in[5];
  const float* ln1_g  = (const float*)d_in[6];
  const float* ln1_b  = (const float*)d_in[7];
  const float* ln2_g  = (const float*)d_in[8];
  const float* ln2_b  = (const float*)d_in[9];
  const float* mlp_w1 = (const float*)d_in[10];
  const float* mlp_b1 = (const float*)d_in[11];
  const float* mlp_w2 = (const float*)d_in[12];
  const float* mlp_b2 = (const float*)d_in[13];
  float* out = (float*)d_out;

  char* ws = (char*)d_ws;
  size_t off = 0;
  auto alloc = [&](size_t bytes) -> void* {
    void* p = ws + off;
    off = (off + bytes + 255) & ~(size_t)255;
    return p;
  };

  bf16* kqv_wb  = (bf16*)alloc(12288 * 2);
  bf16* proj_wb = (bf16*)alloc(262144 * 2);
  bf16* w1b     = (bf16*)alloc(1048576 * 2);
  bf16* w2b     = (bf16*)alloc(1048576 * 2);
  bf16* hb      = (bf16*)alloc((size_t)NTOK * EMB * 2);   // LN1 out; reused as y
  bf16* yb      = hb;
  float* qpb    = (float*)alloc((size_t)NROW * 32 * 4);   // reused as h2 (bf16)
  bf16* h2b     = (bf16*)qpb;
  size_t hid_off = off;                                    // hid spans from here
  float* kpb    = (float*)alloc((size_t)NROW * 32 * 4);   // kp; +vb reused as hid
  bf16* hidb    = (bf16*)kpb;
  bf16* vb      = (bf16*)alloc((size_t)NROW * 64 * 2);     // contiguous after kpb
  float* partb  = (float*)alloc((size_t)64 * KNC * 2080 * 4);  // kptv partials

  // full-hid path needs 32768*2048*2 = 134.2 MB starting at hid_off
  // (kp/v/part all dead by MLP time); guard on actual workspace size.
  const size_t hid_full_bytes = (size_t)NTOK * 2048 * 2;
  const bool full_mlp = ws_size >= hid_off + hid_full_bytes;

  // 1) weights -> bf16 (single fused launch; 4 elems/thread via float4)
  f2b4_kernel<<<1024, 256, 0, stream>>>(kqv_w, kqv_wb, 12288 / 4,
                                        proj_w, proj_wb, 262144 / 4,
                                        mlp_w1, w1b, 1048576 / 4,
                                        mlp_w2, w2b, 1048576 / 4);

  // 2) LN1: x -> h (bf16)
  ln_kernel<<<NTOK / 4, 256, 0, stream>>>(x, ln1_g, ln1_b, hb);

  // 3) fused KQV GEMM + prm_exp -> kp, qp (fp32), v (bf16), per-(b,h) layouts
  kqv_prm_kernel<<<NROW / 64, 256, 0, stream>>>(hb, kqv_wb, kqv_b, w, kpb, qpb, vb);

  // 4) kptv + kp_sum partials (no atomics, no memset)
  kptv_kernel<<<dim3(64, KNC), 256, 0, stream>>>(vb, kpb, partb);

  // 5) y (bf16, token-major [NTOK, 512]) -> reuses hb; sums partials inline
  y_kernel<<<dim3(64, 8), 256, 0, stream>>>(qpb, partb, yb);

  // 6) proj GEMM + residual: d_out = y @ proj_w^T + proj_b + x
  gemm_bt<128, 128, 2, 2, 1><<<dim3(4, NTOK / 128), 256, 0, stream>>>(
      yb, proj_wb, proj_b, x, out, nullptr, NTOK, 512, 512);

  // 7) LN2: d_out -> h2 (bf16, reuses qp region)
  ln_kernel<<<NTOK / 4, 256, 0, stream>>>(out, ln2_g, ln2_b, h2b);

  // 8) MLP: W1 (GELU, bf16 hid) then W2 (+bias+residual, fp32 out).
  //    Single launch pair when workspace holds full hid; else 2 chunks (r4).
  if (full_mlp) {
    gemm_bt<128, 128, 2, 2, 2><<<dim3(16, 256), 256, 0, stream>>>(
        h2b, w1b, mlp_b1, nullptr, nullptr, hidb, NTOK, 2048, 512);
    gemm_bt<64, 128, 1, 4, 1><<<dim3(4, 512), 256, 0, stream>>>(
        hidb, w2b, mlp_b2, out, out, nullptr, NTOK, 512, 2048);
  } else {
    for (int c = 0; c < 2; ++c) {
      const bf16* h2c = h2b + (size_t)c * 16384 * 512;
      float* outc = out + (size_t)c * 16384 * 512;
      gemm_bt<128, 128, 2, 2, 2><<<dim3(16, 128), 256, 0, stream>>>(
          h2c, w1b, mlp_b1, nullptr, nullptr, hidb, 16384, 2048, 512);
      gemm_bt<64, 128, 1, 4, 1><<<dim3(4, 256), 256, 0, stream>>>(
          hidb, w2b, mlp_b2, outc, outc, nullptr, 16384, 512, 2048);
    }
  }
}